// Round 15
// baseline (276.069 us; speedup 1.0000x reference)
//
#include <hip/hip_runtime.h>

typedef unsigned short u16;
typedef unsigned int   u32;
typedef u16  u16x2 __attribute__((ext_vector_type(2)));
typedef u16  u16x4 __attribute__((ext_vector_type(4)));
typedef u16  u16x8 __attribute__((ext_vector_type(8)));
typedef short s8v  __attribute__((ext_vector_type(8)));   // 8 bf16, MFMA A/B frag (K=32 shapes)
typedef short s4v  __attribute__((ext_vector_type(4)));   // 4 bf16, MFMA A/B frag (K=16 shapes)
typedef float f4v  __attribute__((ext_vector_type(4)));   // MFMA C/D frag
typedef u32  u32x2 __attribute__((ext_vector_type(2)));

#define L_SEQ 2048
#define B_SZ  4
#define E_DIM 512
#define H_CNT 8
#define HD    64
#define HID   2048
#define M_ROWS (L_SEQ * B_SZ)   // 8192
#define QSCALE 0.18033688011112042f   // 0.125 * log2(e)

__device__ __forceinline__ u16 f2b(float f) {
    unsigned u = __builtin_bit_cast(unsigned, f);
    u += 0x7fffu + ((u >> 16) & 1u);               // RNE
    return (u16)(u >> 16);
}
__device__ __forceinline__ float b2f(u16 u) {
    u32 x = ((u32)u) << 16; return __builtin_bit_cast(float, x);
}
#if defined(__has_builtin)
#if __has_builtin(__builtin_amdgcn_cvt_pk_bf16_f32)
#define HAVE_PK_BF16 1
#endif
#endif
__device__ __forceinline__ u32 pk_trunc(float a, float b) {
#ifdef HAVE_PK_BF16
    typedef __bf16 bf2 __attribute__((ext_vector_type(2)));
    bf2 r = __builtin_amdgcn_cvt_pk_bf16_f32(a, b);
    return __builtin_bit_cast(u32, r);
#else
    u32 ua = __builtin_bit_cast(u32, a), ub = __builtin_bit_cast(u32, b);
    return (ua >> 16) | (ub & 0xffff0000u);
#endif
}
__device__ __forceinline__ void gload_lds16(const u16* g, u16* l) {
    __builtin_amdgcn_global_load_lds((__attribute__((address_space(1))) void*)(u16*)g,
                                     (__attribute__((address_space(3))) void*)l, 16, 0, 0);
}
// tanh-GELU in sigmoid form (|err| < 1e-3, below bf16 rounding of the result)
__device__ __forceinline__ float gelu_f(float v) {
    float y2 = v * (1.5957691216f + 0.0713548576f * v * v);
    return v / (1.0f + __expf(-y2));
}

// ---------------------------------------------------------------- PE table (b,e) -> 2048 floats
__global__ __launch_bounds__(256) void pe_tab_k(float* __restrict__ pet) {
    int i = blockIdx.x * 256 + threadIdx.x;          // 2048
    int e = i & (E_DIM - 1);
    float t = (float)(i >> 9) + 1.0f;
    int ee = (e & 1) ? (e + 1) : e;
    float w = exp2f((-(float)ee / 512.0f) * 13.287712379549449f);
    pet[i] = (e & 1) ? cosf(t * w) : sinf(t * w);
}

__global__ __launch_bounds__(256) void pe_add_k(const float* __restrict__ x,
                                                const float* __restrict__ pet,
                                                u16* __restrict__ xpb) {
    int idx = (blockIdx.x * 256 + threadIdx.x) * 4;
    f4v v = *(const f4v*)(x + idx);
    f4v p = *(const f4v*)(pet + (idx & 2047));
    u16x4 o;
#pragma unroll
    for (int i = 0; i < 4; ++i) o[i] = f2b(v[i] + p[i]);
    *(u16x4*)(xpb + idx) = o;
}

__global__ __launch_bounds__(256) void conv4_k(const float* __restrict__ s1, u16* __restrict__ d1, int n1,
                                               const float* __restrict__ s2, u16* __restrict__ d2, int n2,
                                               const float* __restrict__ s3, u16* __restrict__ d3, int n3,
                                               const float* __restrict__ s4, u16* __restrict__ d4) {
    int o = (blockIdx.x * 256 + threadIdx.x) * 4;
    const float* s; u16* d;
    if (o < n1) { s = s1; d = d1; }
    else { o -= n1;
        if (o < n2) { s = s2; d = d2; }
        else { o -= n2;
            if (o < n3) { s = s3; d = d3; }
            else { o -= n3; s = s4; d = d4; } } }
    f4v v = *(const f4v*)(s + o);
    u16x4 q;
#pragma unroll
    for (int i = 0; i < 4; ++i) q[i] = f2b(v[i]);
    *(u16x4*)(d + o) = q;
}

// ---------------------------------------------------------------- LN combine (wave per row)
template <int NP, bool WRITEF, bool WRITEB>
__global__ __launch_bounds__(256)
void ln_c(const u16* __restrict__ p0, const u16* __restrict__ p1,
          const u16* __restrict__ p2, const u16* __restrict__ p3,
          const float* __restrict__ bias, const u16* __restrict__ resid,
          const float* __restrict__ gw, const float* __restrict__ bw,
          float* __restrict__ outF, u16* __restrict__ outB) {
    int wave = threadIdx.x >> 6, lane = threadIdx.x & 63;
    size_t row = (size_t)blockIdx.x * 4 + wave;
    size_t off = row * E_DIM + lane * 8;
    u16x8 rv = *(const u16x8*)(resid + off);
    f4v a, b;
#pragma unroll
    for (int i = 0; i < 4; ++i) { a[i] = b2f(rv[i]); b[i] = b2f(rv[i + 4]); }
    a += *(const f4v*)(bias + lane * 8);
    b += *(const f4v*)(bias + lane * 8 + 4);
    const u16* ps[4] = {p0, p1, p2, p3};
#pragma unroll
    for (int z = 0; z < NP; ++z) {
        u16x8 t = *(const u16x8*)(ps[z] + off);
#pragma unroll
        for (int i = 0; i < 4; ++i) { a[i] += b2f(t[i]); b[i] += b2f(t[i + 4]); }
    }
    float s = (a[0] + a[1]) + (a[2] + a[3]) + (b[0] + b[1]) + (b[2] + b[3]);
#pragma unroll
    for (int o = 1; o < 64; o <<= 1) s += __shfl_xor(s, o, 64);
    float mu = s * (1.0f / E_DIM);
    float q = 0.f;
#pragma unroll
    for (int i = 0; i < 4; ++i) { float d = a[i] - mu; q += d * d; }
#pragma unroll
    for (int i = 0; i < 4; ++i) { float d = b[i] - mu; q += d * d; }
#pragma unroll
    for (int o = 1; o < 64; o <<= 1) q += __shfl_xor(q, o, 64);
    float rstd = rsqrtf(q * (1.0f / E_DIM) + 1e-5f);
    f4v g0 = *(const f4v*)(gw + lane * 8), g1 = *(const f4v*)(gw + lane * 8 + 4);
    f4v w0 = *(const f4v*)(bw + lane * 8), w1 = *(const f4v*)(bw + lane * 8 + 4);
    f4v y0, y1;
#pragma unroll
    for (int i = 0; i < 4; ++i) { y0[i] = (a[i] - mu) * rstd * g0[i] + w0[i];
                                  y1[i] = (b[i] - mu) * rstd * g1[i] + w1[i]; }
    if (WRITEF) {
        *(f4v*)(outF + off)     = y0;
        *(f4v*)(outF + off + 4) = y1;
    }
    if (WRITEB) {
        u16x8 o;
#pragma unroll
        for (int i = 0; i < 4; ++i) { o[i] = f2b(y0[i]); o[i + 4] = f2b(y1[i]); }
        *(u16x8*)(outB + off) = o;
    }
}

// ---------------------------------------------------------------- V transpose [b][h][l][d] -> [b][h][d][l]
__global__ __launch_bounds__(256) void transpose_v_k(const u16* __restrict__ vb,
                                                     u16* __restrict__ vt) {
    __shared__ __align__(16) u16 T[64 * 66];
    int t = threadIdx.x;
    int lt = blockIdx.x, bh = blockIdx.y;
    const u16* src = vb + (size_t)bh * (L_SEQ * HD) + (size_t)lt * 64 * HD;
    int lr = t >> 2, d0 = (t & 3) * 16;
    s8v va = *(const s8v*)(src + lr * HD + d0);
    s8v vb8 = *(const s8v*)(src + lr * HD + d0 + 8);
#pragma unroll
    for (int c = 0; c < 4; ++c) {
        u16x2 p0; p0[0] = (u16)va[c * 2]; p0[1] = (u16)va[c * 2 + 1];
        u16x2 p1; p1[0] = (u16)vb8[c * 2]; p1[1] = (u16)vb8[c * 2 + 1];
        *(u16x2*)(&T[lr * 66 + d0 + c * 2])     = p0;
        *(u16x2*)(&T[lr * 66 + d0 + 8 + c * 2]) = p1;
    }
    __syncthreads();
    int d = t >> 2, l0 = (t & 3) * 16;
    u16 tmp[16];
#pragma unroll
    for (int i = 0; i < 16; ++i) tmp[i] = T[(l0 + i) * 66 + d];
    u16* dst = vt + (size_t)bh * (L_SEQ * HD) + (size_t)d * L_SEQ + lt * 64 + l0;
    u16x8 o0, o1;
#pragma unroll
    for (int i = 0; i < 8; ++i) { o0[i] = tmp[i]; o1[i] = tmp[8 + i]; }
    *(u16x8*)dst       = o0;
    *(u16x8*)(dst + 8) = o1;
}

// ---------------------------------------------------------------- GEMM 128x128 BK32 dbuf + XCD swizzle
// KK: compile-time K -> fully-unrolled loop, LDS/global addresses fold to immediates.
// NT = n-tiles. MODE 0: QKV scatter (Q pre-scaled); MODE 2: tanh-GELU bf16.
template <int MODE, int NT, int KK>
__global__ __launch_bounds__(256, 4)
void gemm_bt(const u16* __restrict__ A, const u16* __restrict__ Bw,
             const float* __restrict__ bias, int M, int N,
             u16* __restrict__ outB,
             u16* __restrict__ oq, u16* __restrict__ okk, u16* __restrict__ ov) {
    __shared__ __align__(16) u16 As[2][128 * 32];
    __shared__ __align__(16) u16 Bs[2][128 * 32];
    const int tid = threadIdx.x;
    const int wave = tid >> 6, lane = tid & 63;
    const int col = lane & 15, quad = lane >> 4;
    const int n = blockIdx.x;
    const int xcd = n & 7, loc = n >> 3;
    const int mpx = (M / 128) >> 3;
    const int bm = (xcd * mpx + loc / NT) * 128;
    const int bn = (loc % NT) * 128;
    const int wm = (wave >> 1) * 64, wn = (wave & 1) * 64;
    f4v acc[4][4] = {};
    const int srow = wave * 16 + (lane >> 2);
    const int soff = (lane & 3) * 8;
    const u16* Ag = A + (size_t)(bm + srow) * KK + soff;
    const u16* Bg = Bw + (size_t)(bn + srow) * KK + soff;
    const int wo = wave * 512;
    gload_lds16(Ag,                   &As[0][wo]);
    gload_lds16(Ag + (size_t)64 * KK, &As[0][wo + 2048]);
    gload_lds16(Bg,                   &Bs[0][wo]);
    gload_lds16(Bg + (size_t)64 * KK, &Bs[0][wo + 2048]);
    constexpr int NIT = KK >> 5;
#pragma unroll
    for (int t = 0; t < NIT; ++t) {
        const int cur = t & 1, nxt = cur ^ 1;
        __syncthreads();
        if (t + 1 < NIT) {
            const int kc = (t + 1) * 32;
            gload_lds16(Ag + kc,                   &As[nxt][wo]);
            gload_lds16(Ag + (size_t)64 * KK + kc, &As[nxt][wo + 2048]);
            gload_lds16(Bg + kc,                   &Bs[nxt][wo]);
            gload_lds16(Bg + (size_t)64 * KK + kc, &Bs[nxt][wo + 2048]);
        }
        s8v af[4], bf[4];
#pragma unroll
        for (int i = 0; i < 4; ++i) af[i] = *(const s8v*)(&As[cur][(wm + i * 16 + col) * 32 + quad * 8]);
#pragma unroll
        for (int j = 0; j < 4; ++j) bf[j] = *(const s8v*)(&Bs[cur][(wn + j * 16 + col) * 32 + quad * 8]);
#pragma unroll
        for (int i = 0; i < 4; ++i)
#pragma unroll
            for (int j = 0; j < 4; ++j)
                acc[i][j] = __builtin_amdgcn_mfma_f32_16x16x32_bf16(af[i], bf[j], acc[i][j], 0, 0, 0);
    }
#pragma unroll
    for (int j = 0; j < 4; ++j) {
        int gn = bn + wn + j * 16 + col;
        float bv = bias[gn];
        int which = gn >> 9, hh = (gn >> 6) & 7, d = gn & 63;
        u16* dst = (MODE == 0) ? ((which == 0) ? oq : ((which == 1) ? okk : ov)) : outB;
        float qs = (MODE == 0 && which == 0) ? QSCALE : 1.0f;
#pragma unroll
        for (int i = 0; i < 4; ++i) {
            int gm0 = bm + wm + i * 16 + quad * 4;
#pragma unroll
            for (int r = 0; r < 4; ++r) {
                float v = acc[i][j][r] + bv;
                int m = gm0 + r;
                if (MODE == 2) {
                    outB[(size_t)m * N + gn] = f2b(gelu_f(v));
                } else {
                    int l = m >> 2, bb = m & 3;
                    dst[((size_t)(bb * H_CNT + hh) * L_SEQ + l) * HD + d] = f2b(v * qs);
                }
            }
        }
    }
}

// ---------------------------------------------------------------- K-split partial GEMM BK32 dbuf + XCD swizzle
// KTOT: full K (row stride); KPER: compile-time K-slice -> unrolled loop.
template <int KTOT, int KPER>
__global__ __launch_bounds__(256, 4)
void gemm_ks(const u16* __restrict__ A, const u16* __restrict__ Bw, int N,
             u16* __restrict__ q0, u16* __restrict__ q1) {
    __shared__ __align__(16) u16 As[2][128 * 32];
    __shared__ __align__(16) u16 Bs[2][128 * 32];
    const int tid = threadIdx.x;
    const int wave = tid >> 6, lane = tid & 63;
    const int col = lane & 15, quad = lane >> 4;
    const int n = blockIdx.x;
    const int xcd = n & 7, loc = n >> 3;             // loc in [0,64)
    const int bn = (loc & 3) * 128;
    const int bm = (xcd * 8 + ((loc >> 2) & 7)) * 128;
    const int kz = loc >> 5;
    u16* pz = kz ? q1 : q0;
    const int wm = (wave >> 1) * 64, wn = (wave & 1) * 64;
    f4v acc[4][4] = {};
    const int srow = wave * 16 + (lane >> 2);
    const int soff = (lane & 3) * 8;
    const u16* Ag = A + (size_t)(bm + srow) * KTOT + kz * KPER + soff;
    const u16* Bg = Bw + (size_t)(bn + srow) * KTOT + kz * KPER + soff;
    const int wo = wave * 512;
    gload_lds16(Ag,                     &As[0][wo]);
    gload_lds16(Ag + (size_t)64 * KTOT, &As[0][wo + 2048]);
    gload_lds16(Bg,                     &Bs[0][wo]);
    gload_lds16(Bg + (size_t)64 * KTOT, &Bs[0][wo + 2048]);
    constexpr int NIT = KPER >> 5;
#pragma unroll
    for (int t = 0; t < NIT; ++t) {
        const int cur = t & 1, nxt = cur ^ 1;
        __syncthreads();
        if (t + 1 < NIT) {
            const int kc = (t + 1) * 32;
            gload_lds16(Ag + kc,                     &As[nxt][wo]);
            gload_lds16(Ag + (size_t)64 * KTOT + kc, &As[nxt][wo + 2048]);
            gload_lds16(Bg + kc,                     &Bs[nxt][wo]);
            gload_lds16(Bg + (size_t)64 * KTOT + kc, &Bs[nxt][wo + 2048]);
        }
        s8v af[4], bf[4];
#pragma unroll
        for (int i = 0; i < 4; ++i) af[i] = *(const s8v*)(&As[cur][(wm + i * 16 + col) * 32 + quad * 8]);
#pragma unroll
        for (int j = 0; j < 4; ++j) bf[j] = *(const s8v*)(&Bs[cur][(wn + j * 16 + col) * 32 + quad * 8]);
#pragma unroll
        for (int i = 0; i < 4; ++i)
#pragma unroll
            for (int j = 0; j < 4; ++j)
                acc[i][j] = __builtin_amdgcn_mfma_f32_16x16x32_bf16(af[i], bf[j], acc[i][j], 0, 0, 0);
    }
#pragma unroll
    for (int j = 0; j < 4; ++j) {
        int gn = bn + wn + j * 16 + col;
#pragma unroll
        for (int i = 0; i < 4; ++i) {
            int m0 = bm + wm + i * 16 + quad * 4;
#pragma unroll
            for (int r = 0; r < 4; ++r)
                pz[(size_t)(m0 + r) * N + gn] = f2b(acc[i][j][r]);
        }
    }
}

// ---------------------------------------------------------------- flash attention v6 + unrolled kt loop
__global__ __launch_bounds__(256, 4)
void attn_k(const u16* __restrict__ qg, const u16* __restrict__ kg,
            const u16* __restrict__ vtg,
            u16* __restrict__ po0, u16* __restrict__ po1,
            u16* __restrict__ po2, u16* __restrict__ po3, float* __restrict__ lbuf) {
    __shared__ __align__(16) u16 Ks[2][2][64 * 32];
    __shared__ __align__(16) u16 Vs[2][2][64 * 32];
    const int tid = threadIdx.x;
    const int wave = tid >> 6, lane = tid & 63;
    const int col = lane & 15, quad = lane >> 4;
    const int qc = blockIdx.x, kz = blockIdx.y, bh = blockIdx.z;
    const size_t base = (size_t)bh * (L_SEQ * HD);
    s8v qf[2][2];
#pragma unroll
    for (int t = 0; t < 2; ++t) {
        const int qrow = qc * 128 + wave * 32 + t * 16 + col;
#pragma unroll
        for (int hh = 0; hh < 2; ++hh)
            qf[t][hh] = *(const s8v*)(qg + base + (size_t)qrow * HD + hh * 32 + quad * 8);
    }
    f4v oa[2][4] = {};
    f4v la[2] = {};
    const s4v vones = {0x3F80, 0x3F80, 0x3F80, 0x3F80};   // bf16 1.0 x4
    const int h = wave & 1, r0 = (wave >> 1) * 16;
    const int srow = lane >> 2, c = lane & 3;
    const int cp = c ^ ((srow >> 1) & 3);            // XOR-swizzled 16B chunk fetch
    const u16* Kg = kg + base + (size_t)(r0 + srow) * HD + h * 32 + cp * 8;
    const u16* Vg = vtg + base + (size_t)(r0 + srow) * L_SEQ + h * 32 + cp * 8;
    const int kt0 = kz * 8;
    {
        const int kv0 = kt0 * 64;
        gload_lds16(Kg + (size_t)kv0 * HD,        &Ks[0][h][r0 * 32]);
        gload_lds16(Kg + (size_t)(kv0 + 32) * HD, &Ks[0][h][(r0 + 32) * 32]);
        gload_lds16(Vg + kv0,                     &Vs[0][h][r0 * 32]);
        gload_lds16(Vg + kv0 + (size_t)32 * L_SEQ,&Vs[0][h][(r0 + 32) * 32]);
    }
    const int perm = (col >> 1) & 3;
#pragma unroll
    for (int it = 0; it < 8; ++it) {
        const int cur = it & 1, nxt = cur ^ 1;
        __syncthreads();
        if (it + 1 < 8) {
            const int kv0 = (kt0 + it + 1) * 64;
            gload_lds16(Kg + (size_t)kv0 * HD,        &Ks[nxt][h][r0 * 32]);
            gload_lds16(Kg + (size_t)(kv0 + 32) * HD, &Ks[nxt][h][(r0 + 32) * 32]);
            gload_lds16(Vg + kv0,                     &Vs[nxt][h][r0 * 32]);
            gload_lds16(Vg + kv0 + (size_t)32 * L_SEQ,&Vs[nxt][h][(r0 + 32) * 32]);
        }
        f4v st[2][4];
#pragma unroll
        for (int j = 0; j < 4; ++j) {
            s8v k0 = *(const s8v*)(&Ks[cur][0][(j * 16 + col) * 32 + ((quad ^ perm) * 8)]);
            s8v k1 = *(const s8v*)(&Ks[cur][1][(j * 16 + col) * 32 + ((quad ^ perm) * 8)]);
#pragma unroll
            for (int t = 0; t < 2; ++t) {
                f4v z = {};
                z = __builtin_amdgcn_mfma_f32_16x16x32_bf16(k0, qf[t][0], z, 0, 0, 0);
                z = __builtin_amdgcn_mfma_f32_16x16x32_bf16(k1, qf[t][1], z, 0, 0, 0);
                st[t][j] = z;
            }
        }
        s4v pt[2][4];
#pragma unroll
        for (int t = 0; t < 2; ++t)
#pragma unroll
            for (int j = 0; j < 4; ++j) {
                f4v p;
#pragma unroll
                for (int r = 0; r < 4; ++r) p[r] = exp2f(st[t][j][r]);
                u32x2 pk;
                pk[0] = pk_trunc(p[0], p[1]);
                pk[1] = pk_trunc(p[2], p[3]);
                pt[t][j] = __builtin_bit_cast(s4v, pk);
            }
#pragma unroll
        for (int cc = 0; cc < 4; ++cc) {
            const int hh = cc >> 1;
            const int ch8 = (cc & 1) * 2 + (quad >> 1);
#pragma unroll
            for (int dj = 0; dj < 4; ++dj) {
                s4v vf = *(const s4v*)(&Vs[cur][hh][(dj * 16 + col) * 32 + ((ch8 ^ perm) * 8) + (quad & 1) * 4]);
#pragma unroll
                for (int t = 0; t < 2; ++t)
                    oa[t][dj] = __builtin_amdgcn_mfma_f32_16x16x16bf16_1k(pt[t][cc], vf, oa[t][dj], 0, 0, 0);
            }
#pragma unroll
            for (int t = 0; t < 2; ++t)
                la[t] = __builtin_amdgcn_mfma_f32_16x16x16bf16_1k(pt[t][cc], vones, la[t], 0, 0, 0);
        }
    }
    if (col == 0) {
#pragma unroll
        for (int t = 0; t < 2; ++t)
#pragma unroll
            for (int r = 0; r < 4; ++r)
                lbuf[kz * 65536 + bh * 2048 + (qc * 128 + wave * 32 + t * 16 + quad * 4 + r)] = la[t][r];
    }
    u16* pg = (kz == 0) ? po0 : (kz == 1) ? po1 : (kz == 2) ? po2 : po3;
    const int b = bh >> 3, hd = bh & 7;
#pragma unroll
    for (int t = 0; t < 2; ++t)
#pragma unroll
        for (int r = 0; r < 4; ++r) {
            int lrow = qc * 128 + wave * 32 + t * 16 + quad * 4 + r;
            size_t mrow = (size_t)(lrow * 4 + b) * E_DIM + hd * HD;
#pragma unroll
            for (int dj = 0; dj < 4; ++dj)
                pg[mrow + dj * 16 + col] = f2b(oa[t][dj][r]);
        }
}

// ---------------------------------------------------------------- attention combine
__global__ __launch_bounds__(256)
void combine_k(const u16* __restrict__ p0, const u16* __restrict__ p1,
               const u16* __restrict__ p2, const u16* __restrict__ p3,
               const float* __restrict__ lbuf, u16* __restrict__ out) {
    int idx8 = blockIdx.x * 256 + threadIdx.x;      // 524288
    int m = idx8 >> 6;
    int e0 = (idx8 & 63) * 8;
    int b = m & 3, lrow = m >> 2, h = e0 >> 6;
    int li = (b * 8 + h) * 2048 + lrow;
    float inv = 1.0f / (lbuf[li] + lbuf[65536 + li] + lbuf[131072 + li] + lbuf[196608 + li]);
    size_t off = (size_t)m * E_DIM + e0;
    u16x8 a0 = *(const u16x8*)(p0 + off);
    u16x8 a1 = *(const u16x8*)(p1 + off);
    u16x8 a2 = *(const u16x8*)(p2 + off);
    u16x8 a3 = *(const u16x8*)(p3 + off);
    u16x8 o;
#pragma unroll
    for (int i = 0; i < 8; ++i)
        o[i] = f2b(((b2f(a0[i]) + b2f(a1[i])) + (b2f(a2[i]) + b2f(a3[i]))) * inv);
    *(u16x8*)(out + off) = o;
}

// ---------------------------------------------------------------- host
extern "C" void kernel_launch(void* const* d_in, const int* in_sizes, int n_in,
                              void* d_out, int out_size, void* d_ws, size_t ws_size,
                              hipStream_t stream) {
    const float* x     = (const float*)d_in[0];
    const float* w_qkv = (const float*)d_in[1];
    const float* b_qkv = (const float*)d_in[2];
    const float* w_out = (const float*)d_in[3];
    const float* b_out = (const float*)d_in[4];
    const float* w1    = (const float*)d_in[5];
    const float* b1    = (const float*)d_in[6];
    const float* w2    = (const float*)d_in[7];
    const float* b2    = (const float*)d_in[8];
    const float* ln_g  = (const float*)d_in[9];
    const float* ln_b  = (const float*)d_in[10];

    char* ws = (char*)d_ws;
    u16*   WQKV = (u16*)(ws + 0);                    // 1.5 MB
    u16*   WOUT = (u16*)(ws + 1572864);              // 0.5 MB
    u16*   W1B  = (u16*)(ws + 2097152);              // 2 MB
    u16*   W2B  = (u16*)(ws + 4194304);              // 2 MB
    u16*   XPB  = (u16*)(ws + 6291456);              // 8 MB  x+pe bf16 (resid 1)
    u16*   QB   = (u16*)(ws + 14680064);             // 8 MB
    u16*   KB   = (u16*)(ws + 23068672);             // 8 MB
    u16*   VB   = (u16*)(ws + 31457280);             // 8 MB
    u16*   VT   = (u16*)(ws + 39845888);             // 8 MB
    u16*   AP0  = (u16*)(ws + 48234496);             // 8 MB attn partials
    u16*   AP1  = (u16*)(ws + 56623104);             // 8 MB
    u16*   AP2  = (u16*)(ws + 65011712);             // 8 MB
    u16*   AP3  = (u16*)(ws + 73400320);             // 8 MB
    float* LB   = (float*)(ws + 81788928);           // 1 MB l partials
    float* PET  = (float*)(ws + 82837504);           // 8 KB PE table
    // aliases (disjoint lifetimes):
    u16*   OB   = VB;                                // attn combined out (VB free after transpose)
    u16*   OP0  = (u16*)(ws + 48234496);             // out-proj partials (APx free after combine)
    u16*   OP1  = (u16*)(ws + 56623104);
    u16*   X3B  = QB;                                // LN1 out bf16 (QB free after attn; resid 2)
    u16*   HB   = (u16*)(ws + 48234496);             // FFN1 out 32MB (over OPx, free after ln_c)
    u16*   FP0  = XPB;                               // FFN2 partials (free by FFN2)
    u16*   FP1  = KB;

    pe_tab_k<<<8, 256, 0, stream>>>(PET);
    pe_add_k<<<4096, 256, 0, stream>>>(x, PET, XPB);
    conv4_k<<<3072, 256, 0, stream>>>(w_qkv, WQKV, 3 * E_DIM * E_DIM,
                                      w_out, WOUT, E_DIM * E_DIM,
                                      w1, W1B, HID * E_DIM,
                                      w2, W2B);
    gemm_bt<0, 12, 512><<<768, 256, 0, stream>>>(XPB, WQKV, b_qkv, M_ROWS, 3 * E_DIM,
                                                 nullptr, QB, KB, VB);
    transpose_v_k<<<dim3(32, 32), 256, 0, stream>>>(VB, VT);
    attn_k<<<dim3(16, 4, 32), 256, 0, stream>>>(QB, KB, VT, AP0, AP1, AP2, AP3, LB);
    combine_k<<<2048, 256, 0, stream>>>(AP0, AP1, AP2, AP3, LB, OB);
    gemm_ks<512, 256><<<512, 256, 0, stream>>>(OB, WOUT, E_DIM, OP0, OP1);
    ln_c<2, false, true><<<2048, 256, 0, stream>>>(OP0, OP1, nullptr, nullptr,
                                                   b_out, XPB, ln_g, ln_b, nullptr, X3B);
    gemm_bt<2, 16, 512><<<1024, 256, 0, stream>>>(X3B, W1B, b1, M_ROWS, HID,
                                                  HB, nullptr, nullptr, nullptr);
    gemm_ks<2048, 1024><<<512, 256, 0, stream>>>(HB, W2B, E_DIM, FP0, FP1);
    ln_c<2, true, false><<<2048, 256, 0, stream>>>(FP0, FP1, nullptr, nullptr,
                                                   b2, X3B, ln_g, ln_b, (float*)d_out, nullptr);
}

// Round 16
// 269.255 us; speedup vs baseline: 1.0253x; 1.0253x over previous
//
#include <hip/hip_runtime.h>

typedef unsigned short u16;
typedef unsigned int   u32;
typedef u16  u16x2 __attribute__((ext_vector_type(2)));
typedef u16  u16x4 __attribute__((ext_vector_type(4)));
typedef u16  u16x8 __attribute__((ext_vector_type(8)));
typedef short s8v  __attribute__((ext_vector_type(8)));   // 8 bf16, MFMA A/B frag (K=32 shapes)
typedef short s4v  __attribute__((ext_vector_type(4)));   // 4 bf16, MFMA A/B frag (K=16 shapes)
typedef float f4v  __attribute__((ext_vector_type(4)));   // MFMA C/D frag
typedef u32  u32x2 __attribute__((ext_vector_type(2)));

#define L_SEQ 2048
#define B_SZ  4
#define E_DIM 512
#define H_CNT 8
#define HD    64
#define HID   2048
#define M_ROWS (L_SEQ * B_SZ)   // 8192
#define QSCALE 0.18033688011112042f   // 0.125 * log2(e)

__device__ __forceinline__ u16 f2b(float f) {
    unsigned u = __builtin_bit_cast(unsigned, f);
    u += 0x7fffu + ((u >> 16) & 1u);               // RNE
    return (u16)(u >> 16);
}
__device__ __forceinline__ float b2f(u16 u) {
    u32 x = ((u32)u) << 16; return __builtin_bit_cast(float, x);
}
#if defined(__has_builtin)
#if __has_builtin(__builtin_amdgcn_cvt_pk_bf16_f32)
#define HAVE_PK_BF16 1
#endif
#endif
__device__ __forceinline__ u32 pk_trunc(float a, float b) {
#ifdef HAVE_PK_BF16
    typedef __bf16 bf2 __attribute__((ext_vector_type(2)));
    bf2 r = __builtin_amdgcn_cvt_pk_bf16_f32(a, b);
    return __builtin_bit_cast(u32, r);
#else
    u32 ua = __builtin_bit_cast(u32, a), ub = __builtin_bit_cast(u32, b);
    return (ua >> 16) | (ub & 0xffff0000u);
#endif
}
__device__ __forceinline__ void gload_lds16(const u16* g, u16* l) {
    __builtin_amdgcn_global_load_lds((__attribute__((address_space(1))) void*)(u16*)g,
                                     (__attribute__((address_space(3))) void*)l, 16, 0, 0);
}
// tanh-GELU in sigmoid form (|err| < 1e-3, below bf16 rounding of the result)
__device__ __forceinline__ float gelu_f(float v) {
    float y2 = v * (1.5957691216f + 0.0713548576f * v * v);
    return v / (1.0f + __expf(-y2));
}

// ---------------------------------------------------------------- PE table (b,e) -> 2048 floats
__global__ __launch_bounds__(256) void pe_tab_k(float* __restrict__ pet) {
    int i = blockIdx.x * 256 + threadIdx.x;          // 2048
    int e = i & (E_DIM - 1);
    float t = (float)(i >> 9) + 1.0f;
    int ee = (e & 1) ? (e + 1) : e;
    float w = exp2f((-(float)ee / 512.0f) * 13.287712379549449f);
    pet[i] = (e & 1) ? cosf(t * w) : sinf(t * w);
}

__global__ __launch_bounds__(256) void pe_add_k(const float* __restrict__ x,
                                                const float* __restrict__ pet,
                                                u16* __restrict__ xpb) {
    int idx = (blockIdx.x * 256 + threadIdx.x) * 4;
    f4v v = *(const f4v*)(x + idx);
    f4v p = *(const f4v*)(pet + (idx & 2047));
    u16x4 o;
#pragma unroll
    for (int i = 0; i < 4; ++i) o[i] = f2b(v[i] + p[i]);
    *(u16x4*)(xpb + idx) = o;
}

__global__ __launch_bounds__(256) void conv4_k(const float* __restrict__ s1, u16* __restrict__ d1, int n1,
                                               const float* __restrict__ s2, u16* __restrict__ d2, int n2,
                                               const float* __restrict__ s3, u16* __restrict__ d3, int n3,
                                               const float* __restrict__ s4, u16* __restrict__ d4) {
    int o = (blockIdx.x * 256 + threadIdx.x) * 4;
    const float* s; u16* d;
    if (o < n1) { s = s1; d = d1; }
    else { o -= n1;
        if (o < n2) { s = s2; d = d2; }
        else { o -= n2;
            if (o < n3) { s = s3; d = d3; }
            else { o -= n3; s = s4; d = d4; } } }
    f4v v = *(const f4v*)(s + o);
    u16x4 q;
#pragma unroll
    for (int i = 0; i < 4; ++i) q[i] = f2b(v[i]);
    *(u16x4*)(d + o) = q;
}

// ---------------------------------------------------------------- LN combine (wave per row)
template <int NP, bool WRITEF, bool WRITEB>
__global__ __launch_bounds__(256)
void ln_c(const u16* __restrict__ p0, const u16* __restrict__ p1,
          const u16* __restrict__ p2, const u16* __restrict__ p3,
          const float* __restrict__ bias, const u16* __restrict__ resid,
          const float* __restrict__ gw, const float* __restrict__ bw,
          float* __restrict__ outF, u16* __restrict__ outB) {
    int wave = threadIdx.x >> 6, lane = threadIdx.x & 63;
    size_t row = (size_t)blockIdx.x * 4 + wave;
    size_t off = row * E_DIM + lane * 8;
    u16x8 rv = *(const u16x8*)(resid + off);
    f4v a, b;
#pragma unroll
    for (int i = 0; i < 4; ++i) { a[i] = b2f(rv[i]); b[i] = b2f(rv[i + 4]); }
    a += *(const f4v*)(bias + lane * 8);
    b += *(const f4v*)(bias + lane * 8 + 4);
    const u16* ps[4] = {p0, p1, p2, p3};
#pragma unroll
    for (int z = 0; z < NP; ++z) {
        u16x8 t = *(const u16x8*)(ps[z] + off);
#pragma unroll
        for (int i = 0; i < 4; ++i) { a[i] += b2f(t[i]); b[i] += b2f(t[i + 4]); }
    }
    float s = (a[0] + a[1]) + (a[2] + a[3]) + (b[0] + b[1]) + (b[2] + b[3]);
#pragma unroll
    for (int o = 1; o < 64; o <<= 1) s += __shfl_xor(s, o, 64);
    float mu = s * (1.0f / E_DIM);
    float q = 0.f;
#pragma unroll
    for (int i = 0; i < 4; ++i) { float d = a[i] - mu; q += d * d; }
#pragma unroll
    for (int i = 0; i < 4; ++i) { float d = b[i] - mu; q += d * d; }
#pragma unroll
    for (int o = 1; o < 64; o <<= 1) q += __shfl_xor(q, o, 64);
    float rstd = rsqrtf(q * (1.0f / E_DIM) + 1e-5f);
    f4v g0 = *(const f4v*)(gw + lane * 8), g1 = *(const f4v*)(gw + lane * 8 + 4);
    f4v w0 = *(const f4v*)(bw + lane * 8), w1 = *(const f4v*)(bw + lane * 8 + 4);
    f4v y0, y1;
#pragma unroll
    for (int i = 0; i < 4; ++i) { y0[i] = (a[i] - mu) * rstd * g0[i] + w0[i];
                                  y1[i] = (b[i] - mu) * rstd * g1[i] + w1[i]; }
    if (WRITEF) {
        *(f4v*)(outF + off)     = y0;
        *(f4v*)(outF + off + 4) = y1;
    }
    if (WRITEB) {
        u16x8 o;
#pragma unroll
        for (int i = 0; i < 4; ++i) { o[i] = f2b(y0[i]); o[i + 4] = f2b(y1[i]); }
        *(u16x8*)(outB + off) = o;
    }
}

// ---------------------------------------------------------------- V transpose [b][h][l][d] -> [b][h][d][l]
__global__ __launch_bounds__(256) void transpose_v_k(const u16* __restrict__ vb,
                                                     u16* __restrict__ vt) {
    __shared__ __align__(16) u16 T[64 * 66];
    int t = threadIdx.x;
    int lt = blockIdx.x, bh = blockIdx.y;
    const u16* src = vb + (size_t)bh * (L_SEQ * HD) + (size_t)lt * 64 * HD;
    int lr = t >> 2, d0 = (t & 3) * 16;
    s8v va = *(const s8v*)(src + lr * HD + d0);
    s8v vb8 = *(const s8v*)(src + lr * HD + d0 + 8);
#pragma unroll
    for (int c = 0; c < 4; ++c) {
        u16x2 p0; p0[0] = (u16)va[c * 2]; p0[1] = (u16)va[c * 2 + 1];
        u16x2 p1; p1[0] = (u16)vb8[c * 2]; p1[1] = (u16)vb8[c * 2 + 1];
        *(u16x2*)(&T[lr * 66 + d0 + c * 2])     = p0;
        *(u16x2*)(&T[lr * 66 + d0 + 8 + c * 2]) = p1;
    }
    __syncthreads();
    int d = t >> 2, l0 = (t & 3) * 16;
    u16 tmp[16];
#pragma unroll
    for (int i = 0; i < 16; ++i) tmp[i] = T[(l0 + i) * 66 + d];
    u16* dst = vt + (size_t)bh * (L_SEQ * HD) + (size_t)d * L_SEQ + lt * 64 + l0;
    u16x8 o0, o1;
#pragma unroll
    for (int i = 0; i < 8; ++i) { o0[i] = tmp[i]; o1[i] = tmp[8 + i]; }
    *(u16x8*)dst       = o0;
    *(u16x8*)(dst + 8) = o1;
}

// ---------------------------------------------------------------- GEMM 128x128 BK32 dbuf + XCD swizzle (R14-proven)
// runtime K loop (compiler handles it better than full unroll — R15 lesson).
// NT = n-tiles. MODE 0: QKV scatter (Q pre-scaled); MODE 2: tanh-GELU bf16.
template <int MODE, int NT>
__global__ __launch_bounds__(256, 4)
void gemm_bt(const u16* __restrict__ A, const u16* __restrict__ Bw,
             const float* __restrict__ bias, int M, int N, int K,
             u16* __restrict__ outB,
             u16* __restrict__ oq, u16* __restrict__ okk, u16* __restrict__ ov) {
    __shared__ __align__(16) u16 As[2][128 * 32];
    __shared__ __align__(16) u16 Bs[2][128 * 32];
    const int tid = threadIdx.x;
    const int wave = tid >> 6, lane = tid & 63;
    const int col = lane & 15, quad = lane >> 4;
    const int n = blockIdx.x;
    const int xcd = n & 7, loc = n >> 3;
    const int mpx = (M / 128) >> 3;
    const int bm = (xcd * mpx + loc / NT) * 128;
    const int bn = (loc % NT) * 128;
    const int wm = (wave >> 1) * 64, wn = (wave & 1) * 64;
    f4v acc[4][4] = {};
    const int srow = wave * 16 + (lane >> 2);
    const int soff = (lane & 3) * 8;
    const u16* Ag = A + (size_t)(bm + srow) * K + soff;
    const u16* Bg = Bw + (size_t)(bn + srow) * K + soff;
    const int wo = wave * 512;
    gload_lds16(Ag,                  &As[0][wo]);
    gload_lds16(Ag + (size_t)64 * K, &As[0][wo + 2048]);
    gload_lds16(Bg,                  &Bs[0][wo]);
    gload_lds16(Bg + (size_t)64 * K, &Bs[0][wo + 2048]);
    const int nit = K >> 5;
    for (int t = 0; t < nit; ++t) {
        const int cur = t & 1, nxt = cur ^ 1;
        __syncthreads();
        if (t + 1 < nit) {
            const int kc = (t + 1) * 32;
            gload_lds16(Ag + kc,                  &As[nxt][wo]);
            gload_lds16(Ag + (size_t)64 * K + kc, &As[nxt][wo + 2048]);
            gload_lds16(Bg + kc,                  &Bs[nxt][wo]);
            gload_lds16(Bg + (size_t)64 * K + kc, &Bs[nxt][wo + 2048]);
        }
        s8v af[4], bf[4];
#pragma unroll
        for (int i = 0; i < 4; ++i) af[i] = *(const s8v*)(&As[cur][(wm + i * 16 + col) * 32 + quad * 8]);
#pragma unroll
        for (int j = 0; j < 4; ++j) bf[j] = *(const s8v*)(&Bs[cur][(wn + j * 16 + col) * 32 + quad * 8]);
#pragma unroll
        for (int i = 0; i < 4; ++i)
#pragma unroll
            for (int j = 0; j < 4; ++j)
                acc[i][j] = __builtin_amdgcn_mfma_f32_16x16x32_bf16(af[i], bf[j], acc[i][j], 0, 0, 0);
    }
#pragma unroll
    for (int j = 0; j < 4; ++j) {
        int gn = bn + wn + j * 16 + col;
        float bv = bias[gn];
        int which = gn >> 9, hh = (gn >> 6) & 7, d = gn & 63;
        u16* dst = (MODE == 0) ? ((which == 0) ? oq : ((which == 1) ? okk : ov)) : outB;
        float qs = (MODE == 0 && which == 0) ? QSCALE : 1.0f;
#pragma unroll
        for (int i = 0; i < 4; ++i) {
            int gm0 = bm + wm + i * 16 + quad * 4;
#pragma unroll
            for (int r = 0; r < 4; ++r) {
                float v = acc[i][j][r] + bv;
                int m = gm0 + r;
                if (MODE == 2) {
                    outB[(size_t)m * N + gn] = f2b(gelu_f(v));
                } else {
                    int l = m >> 2, bb = m & 3;
                    dst[((size_t)(bb * H_CNT + hh) * L_SEQ + l) * HD + d] = f2b(v * qs);
                }
            }
        }
    }
}

// ---------------------------------------------------------------- K-split partial GEMM BK32 dbuf + XCD swizzle (R14)
__global__ __launch_bounds__(256, 4)
void gemm_ks(const u16* __restrict__ A, const u16* __restrict__ Bw,
             int N, int K, int Kper,
             u16* __restrict__ q0, u16* __restrict__ q1) {
    __shared__ __align__(16) u16 As[2][128 * 32];
    __shared__ __align__(16) u16 Bs[2][128 * 32];
    const int tid = threadIdx.x;
    const int wave = tid >> 6, lane = tid & 63;
    const int col = lane & 15, quad = lane >> 4;
    const int n = blockIdx.x;
    const int xcd = n & 7, loc = n >> 3;             // loc in [0,64)
    const int bn = (loc & 3) * 128;
    const int bm = (xcd * 8 + ((loc >> 2) & 7)) * 128;
    const int kz = loc >> 5;
    u16* pz = kz ? q1 : q0;
    const int wm = (wave >> 1) * 64, wn = (wave & 1) * 64;
    f4v acc[4][4] = {};
    const int srow = wave * 16 + (lane >> 2);
    const int soff = (lane & 3) * 8;
    const u16* Ag = A + (size_t)(bm + srow) * K + kz * Kper + soff;
    const u16* Bg = Bw + (size_t)(bn + srow) * K + kz * Kper + soff;
    const int wo = wave * 512;
    gload_lds16(Ag,                  &As[0][wo]);
    gload_lds16(Ag + (size_t)64 * K, &As[0][wo + 2048]);
    gload_lds16(Bg,                  &Bs[0][wo]);
    gload_lds16(Bg + (size_t)64 * K, &Bs[0][wo + 2048]);
    const int nit = Kper >> 5;
    for (int t = 0; t < nit; ++t) {
        const int cur = t & 1, nxt = cur ^ 1;
        __syncthreads();
        if (t + 1 < nit) {
            const int kc = (t + 1) * 32;
            gload_lds16(Ag + kc,                  &As[nxt][wo]);
            gload_lds16(Ag + (size_t)64 * K + kc, &As[nxt][wo + 2048]);
            gload_lds16(Bg + kc,                  &Bs[nxt][wo]);
            gload_lds16(Bg + (size_t)64 * K + kc, &Bs[nxt][wo + 2048]);
        }
        s8v af[4], bf[4];
#pragma unroll
        for (int i = 0; i < 4; ++i) af[i] = *(const s8v*)(&As[cur][(wm + i * 16 + col) * 32 + quad * 8]);
#pragma unroll
        for (int j = 0; j < 4; ++j) bf[j] = *(const s8v*)(&Bs[cur][(wn + j * 16 + col) * 32 + quad * 8]);
#pragma unroll
        for (int i = 0; i < 4; ++i)
#pragma unroll
            for (int j = 0; j < 4; ++j)
                acc[i][j] = __builtin_amdgcn_mfma_f32_16x16x32_bf16(af[i], bf[j], acc[i][j], 0, 0, 0);
    }
#pragma unroll
    for (int j = 0; j < 4; ++j) {
        int gn = bn + wn + j * 16 + col;
#pragma unroll
        for (int i = 0; i < 4; ++i) {
            int m0 = bm + wm + i * 16 + quad * 4;
#pragma unroll
            for (int r = 0; r < 4; ++r)
                pz[(size_t)(m0 + r) * N + gn] = f2b(acc[i][j][r]);
        }
    }
}

// ---------------------------------------------------------------- flash attention v6 + unrolled kt loop (R15-proven)
__global__ __launch_bounds__(256, 4)
void attn_k(const u16* __restrict__ qg, const u16* __restrict__ kg,
            const u16* __restrict__ vtg,
            u16* __restrict__ po0, u16* __restrict__ po1,
            u16* __restrict__ po2, u16* __restrict__ po3, float* __restrict__ lbuf) {
    __shared__ __align__(16) u16 Ks[2][2][64 * 32];
    __shared__ __align__(16) u16 Vs[2][2][64 * 32];
    const int tid = threadIdx.x;
    const int wave = tid >> 6, lane = tid & 63;
    const int col = lane & 15, quad = lane >> 4;
    const int qc = blockIdx.x, kz = blockIdx.y, bh = blockIdx.z;
    const size_t base = (size_t)bh * (L_SEQ * HD);
    s8v qf[2][2];
#pragma unroll
    for (int t = 0; t < 2; ++t) {
        const int qrow = qc * 128 + wave * 32 + t * 16 + col;
#pragma unroll
        for (int hh = 0; hh < 2; ++hh)
            qf[t][hh] = *(const s8v*)(qg + base + (size_t)qrow * HD + hh * 32 + quad * 8);
    }
    f4v oa[2][4] = {};
    f4v la[2] = {};
    const s4v vones = {0x3F80, 0x3F80, 0x3F80, 0x3F80};   // bf16 1.0 x4
    const int h = wave & 1, r0 = (wave >> 1) * 16;
    const int srow = lane >> 2, c = lane & 3;
    const int cp = c ^ ((srow >> 1) & 3);            // XOR-swizzled 16B chunk fetch
    const u16* Kg = kg + base + (size_t)(r0 + srow) * HD + h * 32 + cp * 8;
    const u16* Vg = vtg + base + (size_t)(r0 + srow) * L_SEQ + h * 32 + cp * 8;
    const int kt0 = kz * 8;
    {
        const int kv0 = kt0 * 64;
        gload_lds16(Kg + (size_t)kv0 * HD,        &Ks[0][h][r0 * 32]);
        gload_lds16(Kg + (size_t)(kv0 + 32) * HD, &Ks[0][h][(r0 + 32) * 32]);
        gload_lds16(Vg + kv0,                     &Vs[0][h][r0 * 32]);
        gload_lds16(Vg + kv0 + (size_t)32 * L_SEQ,&Vs[0][h][(r0 + 32) * 32]);
    }
    const int perm = (col >> 1) & 3;
#pragma unroll
    for (int it = 0; it < 8; ++it) {
        const int cur = it & 1, nxt = cur ^ 1;
        __syncthreads();
        if (it + 1 < 8) {
            const int kv0 = (kt0 + it + 1) * 64;
            gload_lds16(Kg + (size_t)kv0 * HD,        &Ks[nxt][h][r0 * 32]);
            gload_lds16(Kg + (size_t)(kv0 + 32) * HD, &Ks[nxt][h][(r0 + 32) * 32]);
            gload_lds16(Vg + kv0,                     &Vs[nxt][h][r0 * 32]);
            gload_lds16(Vg + kv0 + (size_t)32 * L_SEQ,&Vs[nxt][h][(r0 + 32) * 32]);
        }
        f4v st[2][4];
#pragma unroll
        for (int j = 0; j < 4; ++j) {
            s8v k0 = *(const s8v*)(&Ks[cur][0][(j * 16 + col) * 32 + ((quad ^ perm) * 8)]);
            s8v k1 = *(const s8v*)(&Ks[cur][1][(j * 16 + col) * 32 + ((quad ^ perm) * 8)]);
#pragma unroll
            for (int t = 0; t < 2; ++t) {
                f4v z = {};
                z = __builtin_amdgcn_mfma_f32_16x16x32_bf16(k0, qf[t][0], z, 0, 0, 0);
                z = __builtin_amdgcn_mfma_f32_16x16x32_bf16(k1, qf[t][1], z, 0, 0, 0);
                st[t][j] = z;
            }
        }
        s4v pt[2][4];
#pragma unroll
        for (int t = 0; t < 2; ++t)
#pragma unroll
            for (int j = 0; j < 4; ++j) {
                f4v p;
#pragma unroll
                for (int r = 0; r < 4; ++r) p[r] = exp2f(st[t][j][r]);
                u32x2 pk;
                pk[0] = pk_trunc(p[0], p[1]);
                pk[1] = pk_trunc(p[2], p[3]);
                pt[t][j] = __builtin_bit_cast(s4v, pk);
            }
#pragma unroll
        for (int cc = 0; cc < 4; ++cc) {
            const int hh = cc >> 1;
            const int ch8 = (cc & 1) * 2 + (quad >> 1);
#pragma unroll
            for (int dj = 0; dj < 4; ++dj) {
                s4v vf = *(const s4v*)(&Vs[cur][hh][(dj * 16 + col) * 32 + ((ch8 ^ perm) * 8) + (quad & 1) * 4]);
#pragma unroll
                for (int t = 0; t < 2; ++t)
                    oa[t][dj] = __builtin_amdgcn_mfma_f32_16x16x16bf16_1k(pt[t][cc], vf, oa[t][dj], 0, 0, 0);
            }
#pragma unroll
            for (int t = 0; t < 2; ++t)
                la[t] = __builtin_amdgcn_mfma_f32_16x16x16bf16_1k(pt[t][cc], vones, la[t], 0, 0, 0);
        }
    }
    if (col == 0) {
#pragma unroll
        for (int t = 0; t < 2; ++t)
#pragma unroll
            for (int r = 0; r < 4; ++r)
                lbuf[kz * 65536 + bh * 2048 + (qc * 128 + wave * 32 + t * 16 + quad * 4 + r)] = la[t][r];
    }
    u16* pg = (kz == 0) ? po0 : (kz == 1) ? po1 : (kz == 2) ? po2 : po3;
    const int b = bh >> 3, hd = bh & 7;
#pragma unroll
    for (int t = 0; t < 2; ++t)
#pragma unroll
        for (int r = 0; r < 4; ++r) {
            int lrow = qc * 128 + wave * 32 + t * 16 + quad * 4 + r;
            size_t mrow = (size_t)(lrow * 4 + b) * E_DIM + hd * HD;
#pragma unroll
            for (int dj = 0; dj < 4; ++dj)
                pg[mrow + dj * 16 + col] = f2b(oa[t][dj][r]);
        }
}

// ---------------------------------------------------------------- attention combine
__global__ __launch_bounds__(256)
void combine_k(const u16* __restrict__ p0, const u16* __restrict__ p1,
               const u16* __restrict__ p2, const u16* __restrict__ p3,
               const float* __restrict__ lbuf, u16* __restrict__ out) {
    int idx8 = blockIdx.x * 256 + threadIdx.x;      // 524288
    int m = idx8 >> 6;
    int e0 = (idx8 & 63) * 8;
    int b = m & 3, lrow = m >> 2, h = e0 >> 6;
    int li = (b * 8 + h) * 2048 + lrow;
    float inv = 1.0f / (lbuf[li] + lbuf[65536 + li] + lbuf[131072 + li] + lbuf[196608 + li]);
    size_t off = (size_t)m * E_DIM + e0;
    u16x8 a0 = *(const u16x8*)(p0 + off);
    u16x8 a1 = *(const u16x8*)(p1 + off);
    u16x8 a2 = *(const u16x8*)(p2 + off);
    u16x8 a3 = *(const u16x8*)(p3 + off);
    u16x8 o;
#pragma unroll
    for (int i = 0; i < 8; ++i)
        o[i] = f2b(((b2f(a0[i]) + b2f(a1[i])) + (b2f(a2[i]) + b2f(a3[i]))) * inv);
    *(u16x8*)(out + off) = o;
}

// ---------------------------------------------------------------- host
extern "C" void kernel_launch(void* const* d_in, const int* in_sizes, int n_in,
                              void* d_out, int out_size, void* d_ws, size_t ws_size,
                              hipStream_t stream) {
    const float* x     = (const float*)d_in[0];
    const float* w_qkv = (const float*)d_in[1];
    const float* b_qkv = (const float*)d_in[2];
    const float* w_out = (const float*)d_in[3];
    const float* b_out = (const float*)d_in[4];
    const float* w1    = (const float*)d_in[5];
    const float* b1    = (const float*)d_in[6];
    const float* w2    = (const float*)d_in[7];
    const float* b2    = (const float*)d_in[8];
    const float* ln_g  = (const float*)d_in[9];
    const float* ln_b  = (const float*)d_in[10];

    char* ws = (char*)d_ws;
    u16*   WQKV = (u16*)(ws + 0);                    // 1.5 MB
    u16*   WOUT = (u16*)(ws + 1572864);              // 0.5 MB
    u16*   W1B  = (u16*)(ws + 2097152);              // 2 MB
    u16*   W2B  = (u16*)(ws + 4194304);              // 2 MB
    u16*   XPB  = (u16*)(ws + 6291456);              // 8 MB  x+pe bf16 (resid 1)
    u16*   QB   = (u16*)(ws + 14680064);             // 8 MB
    u16*   KB   = (u16*)(ws + 23068672);             // 8 MB
    u16*   VB   = (u16*)(ws + 31457280);             // 8 MB
    u16*   VT   = (u16*)(ws + 39845888);             // 8 MB
    u16*   AP0  = (u16*)(ws + 48234496);             // 8 MB attn partials
    u16*   AP1  = (u16*)(ws + 56623104);             // 8 MB
    u16*   AP2  = (u16*)(ws + 65011712);             // 8 MB
    u16*   AP3  = (u16*)(ws + 73400320);             // 8 MB
    float* LB   = (float*)(ws + 81788928);           // 1 MB l partials
    float* PET  = (float*)(ws + 82837504);           // 8 KB PE table
    // aliases (disjoint lifetimes):
    u16*   OB   = VB;                                // attn combined out (VB free after transpose)
    u16*   OP0  = (u16*)(ws + 48234496);             // out-proj partials (APx free after combine)
    u16*   OP1  = (u16*)(ws + 56623104);
    u16*   X3B  = QB;                                // LN1 out bf16 (QB free after attn; resid 2)
    u16*   HB   = (u16*)(ws + 48234496);             // FFN1 out 32MB (over OPx, free after ln_c)
    u16*   FP0  = XPB;                               // FFN2 partials (free by FFN2)
    u16*   FP1  = KB;

    pe_tab_k<<<8, 256, 0, stream>>>(PET);
    pe_add_k<<<4096, 256, 0, stream>>>(x, PET, XPB);
    conv4_k<<<3072, 256, 0, stream>>>(w_qkv, WQKV, 3 * E_DIM * E_DIM,
                                      w_out, WOUT, E_DIM * E_DIM,
                                      w1, W1B, HID * E_DIM,
                                      w2, W2B);
    gemm_bt<0, 12><<<768, 256, 0, stream>>>(XPB, WQKV, b_qkv, M_ROWS, 3 * E_DIM, E_DIM,
                                            nullptr, QB, KB, VB);
    transpose_v_k<<<dim3(32, 32), 256, 0, stream>>>(VB, VT);
    attn_k<<<dim3(16, 4, 32), 256, 0, stream>>>(QB, KB, VT, AP0, AP1, AP2, AP3, LB);
    combine_k<<<2048, 256, 0, stream>>>(AP0, AP1, AP2, AP3, LB, OB);
    gemm_ks<<<512, 256, 0, stream>>>(OB, WOUT, E_DIM, E_DIM, 256, OP0, OP1);
    ln_c<2, false, true><<<2048, 256, 0, stream>>>(OP0, OP1, nullptr, nullptr,
                                                   b_out, XPB, ln_g, ln_b, nullptr, X3B);
    gemm_bt<2, 16><<<1024, 256, 0, stream>>>(X3B, W1B, b1, M_ROWS, HID, E_DIM,
                                             HB, nullptr, nullptr, nullptr);
    gemm_ks<<<512, 256, 0, stream>>>(HB, W2B, E_DIM, HID, 1024, FP0, FP1);
    ln_c<2, true, false><<<2048, 256, 0, stream>>>(FP0, FP1, nullptr, nullptr,
                                                   b2, X3B, ln_g, ln_b, (float*)d_out, nullptr);
}